// Round 2
// baseline (490.113 us; speedup 1.0000x reference)
//
#include <hip/hip_runtime.h>
#include <cstdint>
#include <cstddef>

typedef __bf16 bf16;
typedef __bf16 bf16x2 __attribute__((ext_vector_type(2)));
typedef __bf16 bf16x4 __attribute__((ext_vector_type(4)));
typedef __bf16 bf16x8 __attribute__((ext_vector_type(8)));
typedef float  f32x2 __attribute__((ext_vector_type(2)));
typedef float  f32x4 __attribute__((ext_vector_type(4)));

#define DEVFN __device__ __forceinline__

// async global->LDS, 16B per lane; LDS dest = wave-uniform base + lane*16
DEVFN void gld_lds16(void* lds, const void* g) {
  __builtin_amdgcn_global_load_lds(
      (__attribute__((address_space(1))) void*)g,
      (__attribute__((address_space(3))) void*)lds,
      16, 0, 0);
}

// ---------------- elementwise cast f32 -> bf16 (vectorized x4) ----------------
__global__ void cast_f32_bf16(const float* __restrict__ in, bf16* __restrict__ out, int n4) {
  int i = blockIdx.x * blockDim.x + threadIdx.x;
  if (i < n4) {
    f32x4 v = reinterpret_cast<const f32x4*>(in)[i];
    bf16x4 o;
    o[0] = (bf16)v[0]; o[1] = (bf16)v[1]; o[2] = (bf16)v[2]; o[3] = (bf16)v[3];
    reinterpret_cast<bf16x4*>(out)[i] = o;
  }
}

// ---------------- transpose + cast: in (R x C) f32 -> out (C x R) bf16 --------
__global__ void transpose_cast(const float* __restrict__ in, bf16* __restrict__ out,
                               int R, int C) {
  __shared__ float t[32][33];
  int tx = threadIdx.x, ty = threadIdx.y;
  int c = blockIdx.x * 32 + tx;
  #pragma unroll
  for (int j = 0; j < 4; ++j) {
    int r = blockIdx.y * 32 + ty + j * 8;
    t[ty + j * 8][tx] = in[(size_t)r * C + c];
  }
  __syncthreads();
  int rr = blockIdx.y * 32 + tx;
  #pragma unroll
  for (int j = 0; j < 4; ++j) {
    int cc = blockIdx.x * 32 + ty + j * 8;
    out[(size_t)cc * R + rr] = (bf16)t[tx][ty + j * 8];
  }
}

// ---------------- RoPE cos/sin table: tab[s*64 + 2i]=cos, +1=sin --------------
__global__ void rope_table(float* __restrict__ tab) {
  int idx = blockIdx.x * 256 + threadIdx.x;   // s*32 + i, s<4096, i<32
  int s = idx >> 5, i = idx & 31;
  float theta = powf(10000.f, -(float)(2 * i) * (1.f / 64.f));
  float f = (float)s * theta;
  tab[idx * 2]     = cosf(f);
  tab[idx * 2 + 1] = sinf(f);
}

// ---- GEMM: C(MxN,OT) = A(MxK,bf16) * Bt(NxK,bf16)^T  (m97-structure) ----
template<typename OT>
__global__ __launch_bounds__(256) void gemm_bf16(
    const bf16* __restrict__ A, const bf16* __restrict__ Bt, OT* __restrict__ C,
    int M, int N, int K) {
  __shared__ alignas(16) bf16 As[128 * 64];
  __shared__ alignas(16) bf16 Bs[128 * 64];
  int tid = threadIdx.x;
  int w = tid >> 6, l = tid & 63;
  int l15 = l & 15, lg = l >> 4;
  int m0 = blockIdx.y * 128;
  int n0 = blockIdx.x * 128;
  int wr = (w >> 1) * 64, wc = (w & 1) * 64;
  f32x4 acc[4][4] = {};
  const size_t aBase = (size_t)m0 * K;
  const size_t bBase = (size_t)n0 * K;
  int nk = K >> 6;
  for (int kt = 0; kt < nk; ++kt) {
    int k0 = kt << 6;
    #pragma unroll
    for (int it = 0; it < 4; ++it) {
      int c = it * 256 + tid;
      int row = c >> 3, c8 = c & 7;
      gld_lds16(&As[(size_t)(it * 256 + w * 64) * 8],
                A + aBase + (size_t)row * K + k0 + c8 * 8);
      gld_lds16(&Bs[(size_t)(it * 256 + w * 64) * 8],
                Bt + bBase + (size_t)row * K + k0 + c8 * 8);
    }
    __syncthreads();
    #pragma unroll
    for (int kk = 0; kk < 64; kk += 32) {
      bf16x8 a[4], b[4];
      #pragma unroll
      for (int i = 0; i < 4; ++i)
        a[i] = *reinterpret_cast<const bf16x8*>(&As[(wr + i * 16 + l15) * 64 + kk + lg * 8]);
      #pragma unroll
      for (int i = 0; i < 4; ++i)
        b[i] = *reinterpret_cast<const bf16x8*>(&Bs[(wc + i * 16 + l15) * 64 + kk + lg * 8]);
      #pragma unroll
      for (int mi = 0; mi < 4; ++mi)
        #pragma unroll
        for (int ni = 0; ni < 4; ++ni)
          acc[mi][ni] = __builtin_amdgcn_mfma_f32_16x16x32_bf16(a[mi], b[ni], acc[mi][ni], 0, 0, 0);
    }
    __syncthreads();
  }
  #pragma unroll
  for (int mi = 0; mi < 4; ++mi) {
    #pragma unroll
    for (int r = 0; r < 4; ++r) {
      int row = m0 + wr + mi * 16 + lg * 4 + r;
      OT* crow = C + (size_t)row * N + n0 + wc + l15;
      #pragma unroll
      for (int ni = 0; ni < 4; ++ni) crow[ni * 16] = (OT)acc[mi][ni][r];
    }
  }
}

// ------- RoPE apply + head-split for Q (scaled 0.125) and K (from bf16 qkv) ---
__global__ void rope_qk(const bf16* __restrict__ qkv, const float* __restrict__ tab,
                        bf16* __restrict__ Qb, bf16* __restrict__ Kb) {
  int idx = blockIdx.x * 256 + threadIdx.x;  // ((b*S+s)*16 + h)*32 + i
  int i = idx & 31;
  int h = (idx >> 5) & 15;
  int bs = idx >> 9;
  int s = bs & 4095;
  int b = bs >> 12;
  const bf16* row = qkv + (size_t)bs * 3072;
  bf16x2 q2 = *reinterpret_cast<const bf16x2*>(row + h * 64 + 2 * i);
  bf16x2 k2 = *reinterpret_cast<const bf16x2*>(row + 1024 + h * 64 + 2 * i);
  f32x2 cs = *reinterpret_cast<const f32x2*>(tab + s * 64 + 2 * i);
  float c = cs[0], sn = cs[1];
  float q0 = (float)q2[0], q1 = (float)q2[1];
  float k0 = (float)k2[0], k1 = (float)k2[1];
  size_t ob = (((size_t)(b * 16 + h) * 4096) + s) * 64 + 2 * i;
  bf16x2 qo, ko;
  qo[0] = (bf16)((q0 * c - q1 * sn) * 0.125f);
  qo[1] = (bf16)((q0 * sn + q1 * c) * 0.125f);
  ko[0] = (bf16)(k0 * c - k1 * sn);
  ko[1] = (bf16)(k0 * sn + k1 * c);
  *reinterpret_cast<bf16x2*>(Qb + ob) = qo;
  *reinterpret_cast<bf16x2*>(Kb + ob) = ko;
}

// ---- K reshape (optional) + V transpose from bf16 source:
//      kv (B*Lk x rs) bf16 -> Kdst (B,16,Lk,64) bf16 ; Vt (B,16,64,Lk) bf16 ----
__global__ void kv_post(const bf16* __restrict__ kv, bf16* __restrict__ Kdst,
                        bf16* __restrict__ Vt, int Lk, int rs, int koff, int voff) {
  __shared__ float t[64][65];
  int s0 = blockIdx.x * 64;
  int h = blockIdx.y, b = blockIdx.z;
  int tid = threadIdx.x;
  int lane_d = tid & 63;
  int rq = tid >> 6;
  const bf16* base = kv + (size_t)b * Lk * rs;
  if (Kdst) {
    #pragma unroll
    for (int r = 0; r < 16; ++r) {
      int si = r * 4 + rq;
      Kdst[(((size_t)(b * 16 + h) * Lk) + s0 + si) * 64 + lane_d] =
          base[(size_t)(s0 + si) * rs + koff + h * 64 + lane_d];
    }
  }
  #pragma unroll
  for (int r = 0; r < 16; ++r) {
    int si = r * 4 + rq;
    t[si][lane_d] = (float)base[(size_t)(s0 + si) * rs + voff + h * 64 + lane_d];
  }
  __syncthreads();
  #pragma unroll
  for (int r = 0; r < 16; ++r) {
    int d = r * 4 + rq;
    Vt[(((size_t)(b * 16 + h) * 64) + d) * Lk + s0 + lane_d] = (bf16)t[lane_d][d];
  }
}

// ---------------- flash attention (64-query tile, 4 waves x 16 q) -------------
// Qb pre-scaled by 1/8. Swapped QK^T: mfma(K, Q) -> S^T frags (col=query).
// WINDOWED: causal sliding window of 512 (tile kt==qt causal, kt==qt-8 anticausal).
template<bool WINDOWED>
__global__ __launch_bounds__(256) void attn_kernel(
    const bf16* __restrict__ Qb, const bf16* __restrict__ Kb, const bf16* __restrict__ Vt,
    bf16* __restrict__ outc, int S, int Lk, int col_off) {
  __shared__ alignas(16) bf16 Ks[64 * 64];
  __shared__ alignas(16) bf16 Vs[64 * 64];
  __shared__ alignas(16) bf16 Ps[4][16 * 72];
  int tid = threadIdx.x;
  int w = tid >> 6, l = tid & 63;
  int l15 = l & 15, lg = l >> 4;
  int qt = blockIdx.x, h = blockIdx.y, b = blockIdx.z;

  size_t qrow = (((size_t)(b * 16 + h) * S) + qt * 64 + w * 16 + l15) * 64;
  bf16x8 qf[2];
  qf[0] = *reinterpret_cast<const bf16x8*>(Qb + qrow + lg * 8);
  qf[1] = *reinterpret_cast<const bf16x8*>(Qb + qrow + 32 + lg * 8);
  const bf16* Kbase = Kb + ((size_t)(b * 16 + h) * Lk) * 64;
  const bf16* Vbase = Vt + ((size_t)(b * 16 + h) * 64) * Lk;

  float mrow = -1e30f, lsum = 0.f;
  f32x4 acc[4] = {};

  int kt_hi, kt_lo;
  if (WINDOWED) { kt_hi = qt; kt_lo = qt >= 8 ? qt - 8 : 0; }
  else          { kt_hi = (Lk >> 6) - 1; kt_lo = 0; }

  for (int kt = kt_hi; kt >= kt_lo; --kt) {
    const bf16* kg = Kbase + (size_t)kt * 64 * 64;  // K tile is fully contiguous
    #pragma unroll
    for (int it = 0; it < 2; ++it)
      gld_lds16(&Ks[(it * 256 + w * 64) * 8], kg + (size_t)(it * 256 + tid) * 8);
    #pragma unroll
    for (int it = 0; it < 2; ++it) {
      int c = it * 256 + tid;
      int row = c >> 3, c8 = c & 7;
      gld_lds16(&Vs[(it * 256 + w * 64) * 8],
                Vbase + (size_t)row * Lk + kt * 64 + c8 * 8);
    }
    __syncthreads();

    f32x4 st[4] = {};
    #pragma unroll
    for (int kk = 0; kk < 2; ++kk) {
      #pragma unroll
      for (int f = 0; f < 4; ++f) {
        bf16x8 kf = *reinterpret_cast<const bf16x8*>(&Ks[(f * 16 + l15) * 64 + kk * 32 + lg * 8]);
        st[f] = __builtin_amdgcn_mfma_f32_16x16x32_bf16(kf, qf[kk], st[f], 0, 0, 0);
      }
    }

    if (WINDOWED) {
      int qi = w * 16 + l15;
      if (kt == qt) {
        #pragma unroll
        for (int f = 0; f < 4; ++f)
          #pragma unroll
          for (int r = 0; r < 4; ++r)
            if (f * 16 + lg * 4 + r > qi) st[f][r] = -1e30f;
      } else if (kt == qt - 8) {
        #pragma unroll
        for (int f = 0; f < 4; ++f)
          #pragma unroll
          for (int r = 0; r < 4; ++r)
            if (f * 16 + lg * 4 + r <= qi) st[f][r] = -1e30f;
      }
    }

    float rm = -1e30f;
    #pragma unroll
    for (int f = 0; f < 4; ++f)
      #pragma unroll
      for (int r = 0; r < 4; ++r) rm = fmaxf(rm, st[f][r]);
    rm = fmaxf(rm, __shfl_xor(rm, 16));
    rm = fmaxf(rm, __shfl_xor(rm, 32));
    float mnew = fmaxf(mrow, rm);
    float fsc = __expf(mrow - mnew);
    float ps = 0.f;
    bf16x4 pv[4];
    #pragma unroll
    for (int f = 0; f < 4; ++f)
      #pragma unroll
      for (int r = 0; r < 4; ++r) {
        float p = __expf(st[f][r] - mnew);
        ps += p;
        pv[f][r] = (bf16)p;
      }
    ps += __shfl_xor(ps, 16);
    ps += __shfl_xor(ps, 32);
    lsum = lsum * fsc + ps;
    mrow = mnew;

    #pragma unroll
    for (int f = 0; f < 4; ++f)
      *reinterpret_cast<bf16x4*>(&Ps[w][l15 * 72 + f * 16 + lg * 4]) = pv[f];

    #pragma unroll
    for (int r = 0; r < 4; ++r) {
      float fr = __shfl(fsc, lg * 4 + r);
      #pragma unroll
      for (int f = 0; f < 4; ++f) acc[f][r] *= fr;
    }

    #pragma unroll
    for (int kk = 0; kk < 2; ++kk) {
      bf16x8 pa = *reinterpret_cast<const bf16x8*>(&Ps[w][l15 * 72 + kk * 32 + lg * 8]);
      #pragma unroll
      for (int f = 0; f < 4; ++f) {
        bf16x8 vf = *reinterpret_cast<const bf16x8*>(&Vs[(f * 16 + l15) * 64 + kk * 32 + lg * 8]);
        acc[f] = __builtin_amdgcn_mfma_f32_16x16x32_bf16(pa, vf, acc[f], 0, 0, 0);
      }
    }
    __syncthreads();
  }

  float inv = 1.f / lsum;
  #pragma unroll
  for (int r = 0; r < 4; ++r) {
    float ir = __shfl(inv, lg * 4 + r);
    int srow = qt * 64 + w * 16 + lg * 4 + r;
    bf16* orow = outc + ((size_t)b * S + srow) * 3072 + col_off + h * 64 + l15;
    #pragma unroll
    for (int f = 0; f < 4; ++f) orow[f * 16] = (bf16)(acc[f][r] * ir);
  }
}

// ------------- RMSNorm in-place per (token, 1024-segment), bf16 ---------------
__global__ __launch_bounds__(256) void rmsnorm_kernel(
    bf16* data, const float* __restrict__ g0,
    const float* __restrict__ g1, const float* __restrict__ g2) {
  int token = blockIdx.x;
  int seg = blockIdx.y;
  const float* g = seg == 0 ? g0 : (seg == 1 ? g1 : g2);
  int tid = threadIdx.x;
  size_t base = (size_t)token * 3072 + seg * 1024;
  bf16x4 bv = reinterpret_cast<const bf16x4*>(data + base)[tid];
  f32x4 v;
  #pragma unroll
  for (int j = 0; j < 4; ++j) v[j] = (float)bv[j];
  float ss = v[0] * v[0] + v[1] * v[1] + v[2] * v[2] + v[3] * v[3];
  #pragma unroll
  for (int m = 1; m < 64; m <<= 1) ss += __shfl_xor(ss, m);
  __shared__ float red[4];
  if ((tid & 63) == 0) red[tid >> 6] = ss;
  __syncthreads();
  float tot = red[0] + red[1] + red[2] + red[3];
  float sc = rsqrtf(tot * (1.f / 1024.f) + 1.19209290e-07f);
  f32x4 gv = reinterpret_cast<const f32x4*>(g)[tid];
  bf16x4 o;
  #pragma unroll
  for (int j = 0; j < 4; ++j) o[j] = (bf16)(v[j] * sc * gv[j]);
  reinterpret_cast<bf16x4*>(data + base)[tid] = o;
}

// -------- silu(gate)*value : gv (8192x2048) bf16 -> (8192x1024) bf16 ----------
__global__ void silu_kernel(const bf16* __restrict__ gv, bf16* __restrict__ out) {
  int T = blockIdx.x * 256 + threadIdx.x;
  int row = T >> 8, c4 = (T & 255) * 4;
  bf16x4 g = *reinterpret_cast<const bf16x4*>(gv + (size_t)row * 2048 + c4);
  bf16x4 vv = *reinterpret_cast<const bf16x4*>(gv + (size_t)row * 2048 + 1024 + c4);
  bf16x4 o;
  #pragma unroll
  for (int j = 0; j < 4; ++j) {
    float x = (float)g[j];
    o[j] = (bf16)((x / (1.f + __expf(-x))) * (float)vv[j]);
  }
  *reinterpret_cast<bf16x4*>(out + (size_t)row * 1024 + c4) = o;
}

// =============================== launch ======================================
extern "C" void kernel_launch(void* const* d_in, const int* in_sizes, int n_in,
                              void* d_out, int out_size, void* d_ws, size_t ws_size,
                              hipStream_t stream) {
  (void)in_sizes; (void)n_in; (void)out_size; (void)ws_size;
  const float* x       = (const float*)d_in[0];
  const float* lm      = (const float*)d_in[1];
  const float* arch    = (const float*)d_in[2];
  const float* W_qkv   = (const float*)d_in[3];
  const float* W_lm    = (const float*)d_in[4];
  const float* W_arch  = (const float*)d_in[5];
  const float* W_o     = (const float*)d_in[6];
  const float* W_gate  = (const float*)d_in[7];
  const float* g_local = (const float*)d_in[8];
  const float* g_lm    = (const float*)d_in[9];
  const float* g_arch  = (const float*)d_in[10];
  float* out = (float*)d_out;

  char* ws = (char*)d_ws;
  size_t off = 0;
  auto alloc = [&](size_t bytes) -> void* {
    void* p = ws + off;
    off += (bytes + 255) & ~(size_t)255;
    return p;
  };
  // persistent (~36.5 MB)
  bf16*  Wqkv_t   = (bf16*) alloc(3072ull * 1024 * 2);
  bf16*  Wlm_t    = (bf16*) alloc(2048ull * 1024 * 2);
  bf16*  Warch_t  = (bf16*) alloc(2048ull * 1024 * 2);
  bf16*  Wgate_t  = (bf16*) alloc(2048ull * 3072 * 2);
  bf16*  Wo_t     = (bf16*) alloc(1024ull * 1024 * 2);
  bf16*  lm_bf    = (bf16*) alloc(512ull * 1024 * 2);
  bf16*  arch_bf  = (bf16*) alloc(256ull * 1024 * 2);
  float* ropetab  = (float*)alloc(4096ull * 64 * 4);
  bf16*  Klm      = (bf16*) alloc(2ull * 16 * 256 * 64 * 2);
  bf16*  Vlm_t    = (bf16*) alloc(2ull * 16 * 64 * 256 * 2);
  bf16*  Ka       = (bf16*) alloc(2ull * 16 * 128 * 64 * 2);
  bf16*  Va_t     = (bf16*) alloc(2ull * 16 * 64 * 128 * 2);
  bf16*  lmkv_bf  = (bf16*) alloc(512ull * 2048 * 2);
  bf16*  akv_bf   = (bf16*) alloc(256ull * 2048 * 2);
  // region 1 (16 MB): x_bf, later gated
  char* R1 = (char*)alloc(8192ull * 1024 * 2);
  bf16* x_bf  = (bf16*)R1;
  bf16* gated = (bf16*)R1;          // alias: x_bf dead after QKV GEMM
  // region 2 (48 MB): qkv_bf, later concat (bf16)
  char* R2 = (char*)alloc(8192ull * 3072 * 2);
  bf16* qkv_bf  = (bf16*)R2;
  bf16* concatb = (bf16*)R2;        // alias: qkv_bf dead after rope_qk/kv_post
  // region 3 (48 MB): Qb+Kb+Vt, later gate-GEMM output (32 MB)
  char* R3 = (char*)alloc(3ull * 16 * 1024 * 1024);
  bf16* Qb = (bf16*)R3;
  bf16* Kb = (bf16*)(R3 + 16ull * 1024 * 1024);
  bf16* Vt = (bf16*)(R3 + 32ull * 1024 * 1024);
  bf16* gv = (bf16*)R3;             // alias: Q/K/V dead after attentions

  // 1. weight transposes + input casts + rope table
  transpose_cast<<<dim3(96, 32), dim3(32, 8), 0, stream>>>(W_qkv, Wqkv_t, 1024, 3072);
  transpose_cast<<<dim3(64, 32), dim3(32, 8), 0, stream>>>(W_lm, Wlm_t, 1024, 2048);
  transpose_cast<<<dim3(64, 32), dim3(32, 8), 0, stream>>>(W_arch, Warch_t, 1024, 2048);
  transpose_cast<<<dim3(64, 96), dim3(32, 8), 0, stream>>>(W_gate, Wgate_t, 3072, 2048);
  transpose_cast<<<dim3(32, 32), dim3(32, 8), 0, stream>>>(W_o, Wo_t, 1024, 1024);
  cast_f32_bf16<<<8192, 256, 0, stream>>>(x, x_bf, 8192 * 1024 / 4);
  cast_f32_bf16<<<512, 256, 0, stream>>>(lm, lm_bf, 512 * 1024 / 4);
  cast_f32_bf16<<<256, 256, 0, stream>>>(arch, arch_bf, 256 * 1024 / 4);
  rope_table<<<512, 256, 0, stream>>>(ropetab);

  // 2. projection GEMMs (bf16 outputs)
  gemm_bf16<bf16><<<dim3(24, 64), 256, 0, stream>>>(x_bf, Wqkv_t, qkv_bf, 8192, 3072, 1024);
  gemm_bf16<bf16><<<dim3(16, 4), 256, 0, stream>>>(lm_bf, Wlm_t, lmkv_bf, 512, 2048, 1024);
  gemm_bf16<bf16><<<dim3(16, 2), 256, 0, stream>>>(arch_bf, Warch_t, akv_bf, 256, 2048, 1024);

  // 3. rope + head-split + V transposes
  rope_qk<<<16384, 256, 0, stream>>>(qkv_bf, ropetab, Qb, Kb);
  kv_post<<<dim3(64, 16, 2), 256, 0, stream>>>(qkv_bf, nullptr, Vt, 4096, 3072, 0, 2048);
  kv_post<<<dim3(4, 16, 2), 256, 0, stream>>>(lmkv_bf, Klm, Vlm_t, 256, 2048, 0, 1024);
  kv_post<<<dim3(2, 16, 2), 256, 0, stream>>>(akv_bf, Ka, Va_t, 128, 2048, 0, 1024);

  // 4. attentions -> concat (bf16; overwrites qkv_bf region)
  attn_kernel<true><<<dim3(64, 16, 2), 256, 0, stream>>>(Qb, Kb, Vt, concatb, 4096, 4096, 0);
  attn_kernel<false><<<dim3(64, 16, 2), 256, 0, stream>>>(Qb, Klm, Vlm_t, concatb, 4096, 256, 1024);
  attn_kernel<false><<<dim3(64, 16, 2), 256, 0, stream>>>(Qb, Ka, Va_t, concatb, 4096, 128, 2048);

  // 5. per-branch RMSNorm in place
  rmsnorm_kernel<<<dim3(8192, 3), 256, 0, stream>>>(concatb, g_local, g_lm, g_arch);

  // 6. gate GEMM + silu + output GEMM
  gemm_bf16<bf16><<<dim3(16, 64), 256, 0, stream>>>(concatb, Wgate_t, gv, 8192, 2048, 3072);
  silu_kernel<<<8192, 256, 0, stream>>>(gv, gated);
  gemm_bf16<float><<<dim3(8, 64), 256, 0, stream>>>(gated, Wo_t, out, 8192, 1024, 1024);
}

// Round 3
// 436.314 us; speedup vs baseline: 1.1233x; 1.1233x over previous
//
#include <hip/hip_runtime.h>
#include <cstdint>
#include <cstddef>

typedef __bf16 bf16;
typedef __bf16 bf16x2 __attribute__((ext_vector_type(2)));
typedef __bf16 bf16x4 __attribute__((ext_vector_type(4)));
typedef __bf16 bf16x8 __attribute__((ext_vector_type(8)));
typedef float  f32x2 __attribute__((ext_vector_type(2)));
typedef float  f32x4 __attribute__((ext_vector_type(4)));

#define DEVFN __device__ __forceinline__
#define BAR()  asm volatile("s_barrier" ::: "memory")
#define VMW4() asm volatile("s_waitcnt vmcnt(4)" ::: "memory")

// async global->LDS, 16B per lane; LDS dest = wave-uniform base + lane*16
DEVFN void gld_lds16(void* lds, const void* g) {
  __builtin_amdgcn_global_load_lds(
      (__attribute__((address_space(1))) void*)g,
      (__attribute__((address_space(3))) void*)lds,
      16, 0, 0);
}

// ---------------- elementwise cast f32 -> bf16 (vectorized x4) ----------------
__global__ void cast_f32_bf16(const float* __restrict__ in, bf16* __restrict__ out, int n4) {
  int i = blockIdx.x * blockDim.x + threadIdx.x;
  if (i < n4) {
    f32x4 v = reinterpret_cast<const f32x4*>(in)[i];
    bf16x4 o;
    o[0] = (bf16)v[0]; o[1] = (bf16)v[1]; o[2] = (bf16)v[2]; o[3] = (bf16)v[3];
    reinterpret_cast<bf16x4*>(out)[i] = o;
  }
}

// ---------------- transpose + cast: in (R x C) f32 -> out (C x R) bf16 --------
__global__ void transpose_cast(const float* __restrict__ in, bf16* __restrict__ out,
                               int R, int C) {
  __shared__ float t[32][33];
  int tx = threadIdx.x, ty = threadIdx.y;
  int c = blockIdx.x * 32 + tx;
  #pragma unroll
  for (int j = 0; j < 4; ++j) {
    int r = blockIdx.y * 32 + ty + j * 8;
    t[ty + j * 8][tx] = in[(size_t)r * C + c];
  }
  __syncthreads();
  int rr = blockIdx.y * 32 + tx;
  #pragma unroll
  for (int j = 0; j < 4; ++j) {
    int cc = blockIdx.x * 32 + ty + j * 8;
    out[(size_t)cc * R + rr] = (bf16)t[tx][ty + j * 8];
  }
}

// ---------------- RoPE cos/sin table: tab[s*64 + 2i]=cos, +1=sin --------------
__global__ void rope_table(float* __restrict__ tab) {
  int idx = blockIdx.x * 256 + threadIdx.x;   // s*32 + i, s<4096, i<32
  int s = idx >> 5, i = idx & 31;
  float theta = powf(10000.f, -(float)(2 * i) * (1.f / 64.f));
  float f = (float)s * theta;
  tab[idx * 2]     = cosf(f);
  tab[idx * 2 + 1] = sinf(f);
}

// ====================== 256x256 8-wave deep-pipelined GEMM ====================
// C(MxN,OT) = A(MxK,bf16) * Bt(NxK,bf16)^T. M,N multiples of 256, K of 64.
// grid = (M/256)*(N/256) 1-D (divisible by 8). 512 threads.
// LDS: [buf2][A/B][kk2][256 rows x 32 cols] bf16 = 128 KiB, double-buffered.
// Per K-tile: 4 phases; phase p: {ds_read frags | stage 1 chunk of tile t+1 |
// s_barrier | 16 MFMA (setprio) | [vmcnt(4) end of P1,P3] | s_barrier}.
// XOR swizzle slot^=(row>>1)&3 applied to global source AND ds_read (T2).
template<typename OT>
__global__ __launch_bounds__(512) void gemm256(
    const bf16* __restrict__ A, const bf16* __restrict__ Bt, OT* __restrict__ C,
    int M, int N, int K) {
  __shared__ alignas(16) bf16 lds[2][2][2][256 * 32];
  const int tid = threadIdx.x;
  const int w = tid >> 6, l = tid & 63;
  const int l15 = l & 15, lg = l >> 4;
  const int wm = w >> 2, wn = w & 3;
  // bijective XCD swizzle (gridDim.x % 8 == 0 for all our shapes)
  const int nwg = gridDim.x, qx = nwg >> 3;
  const int swz = (blockIdx.x & 7) * qx + (blockIdx.x >> 3);
  const int gx = N >> 8;
  const int m0 = (swz / gx) << 8;
  const int n0 = (swz % gx) << 8;
  const int nt = K >> 6;

  // stage one 16KB chunk (ab: 0=A,1=B ; kk half) of K-tile t into buf b
  auto stage = [&](int b, int ab, int kk, int t) {
    const bf16* __restrict__ src = ab ? Bt : A;
    const int base0 = ab ? n0 : m0;
    const int k0 = (t << 6) + (kk << 5);
    #pragma unroll
    for (int i = 0; i < 2; ++i) {
      int u = i * 512 + tid;
      int row = u >> 2, slot = u & 3;
      int sslot = slot ^ ((row >> 1) & 3);
      gld_lds16(&lds[b][ab][kk][(i * 512 + w * 64) * 8],
                src + (size_t)(base0 + row) * K + k0 + sslot * 8);
    }
  };
  // swizzled b128 fragment read: row r (0..255), k-slot = lg
  auto rd = [&](int b, int ab, int kk, int r) -> bf16x8 {
    return *reinterpret_cast<const bf16x8*>(
        &lds[b][ab][kk][(r << 5) + ((lg ^ ((r >> 1) & 3)) << 3)]);
  };

  f32x4 acc[8][4] = {};
  bf16x8 afr[4], bfr[4];

  // prologue: stage K-tile 0 fully; S0,S1 must land (vmcnt 8->4)
  stage(0, 0, 0, 0);
  stage(0, 1, 0, 0);
  stage(0, 0, 1, 0);
  stage(0, 1, 1, 0);
  VMW4();
  BAR();

  for (int t = 0; t < nt; ++t) {
    const int c = t & 1;
    const bool st = (t + 1) < nt;
    // ---- P0: kk=0, M-frags 0-3 ----
    #pragma unroll
    for (int f = 0; f < 4; ++f) afr[f] = rd(c, 0, 0, wm * 128 + f * 16 + l15);
    #pragma unroll
    for (int f = 0; f < 4; ++f) bfr[f] = rd(c, 1, 0, wn * 64 + f * 16 + l15);
    if (st) stage(c ^ 1, 0, 0, t + 1);
    BAR();
    __builtin_amdgcn_s_setprio(1);
    #pragma unroll
    for (int mi = 0; mi < 4; ++mi)
      #pragma unroll
      for (int ni = 0; ni < 4; ++ni)
        acc[mi][ni] = __builtin_amdgcn_mfma_f32_16x16x32_bf16(afr[mi], bfr[ni], acc[mi][ni], 0, 0, 0);
    __builtin_amdgcn_s_setprio(0);
    BAR();
    // ---- P1: kk=0, M-frags 4-7 ----
    #pragma unroll
    for (int f = 0; f < 4; ++f) afr[f] = rd(c, 0, 0, wm * 128 + (f + 4) * 16 + l15);
    if (st) stage(c ^ 1, 1, 0, t + 1);
    BAR();
    __builtin_amdgcn_s_setprio(1);
    #pragma unroll
    for (int mi = 0; mi < 4; ++mi)
      #pragma unroll
      for (int ni = 0; ni < 4; ++ni)
        acc[mi + 4][ni] = __builtin_amdgcn_mfma_f32_16x16x32_bf16(afr[mi], bfr[ni], acc[mi + 4][ni], 0, 0, 0);
    __builtin_amdgcn_s_setprio(0);
    VMW4();               // drains old A-kk1/B-kk1 (consumed next phase)
    BAR();
    // ---- P2: kk=1, M-frags 0-3 ----
    #pragma unroll
    for (int f = 0; f < 4; ++f) afr[f] = rd(c, 0, 1, wm * 128 + f * 16 + l15);
    #pragma unroll
    for (int f = 0; f < 4; ++f) bfr[f] = rd(c, 1, 1, wn * 64 + f * 16 + l15);
    if (st) stage(c ^ 1, 0, 1, t + 1);
    BAR();
    __builtin_amdgcn_s_setprio(1);
    #pragma unroll
    for (int mi = 0; mi < 4; ++mi)
      #pragma unroll
      for (int ni = 0; ni < 4; ++ni)
        acc[mi][ni] = __builtin_amdgcn_mfma_f32_16x16x32_bf16(afr[mi], bfr[ni], acc[mi][ni], 0, 0, 0);
    __builtin_amdgcn_s_setprio(0);
    BAR();
    // ---- P3: kk=1, M-frags 4-7 ----
    #pragma unroll
    for (int f = 0; f < 4; ++f) afr[f] = rd(c, 0, 1, wm * 128 + (f + 4) * 16 + l15);
    if (st) stage(c ^ 1, 1, 1, t + 1);
    BAR();
    __builtin_amdgcn_s_setprio(1);
    #pragma unroll
    for (int mi = 0; mi < 4; ++mi)
      #pragma unroll
      for (int ni = 0; ni < 4; ++ni)
        acc[mi + 4][ni] = __builtin_amdgcn_mfma_f32_16x16x32_bf16(afr[mi], bfr[ni], acc[mi + 4][ni], 0, 0, 0);
    __builtin_amdgcn_s_setprio(0);
    VMW4();               // drains next tile's A-kk0/B-kk0 (consumed next P0)
    BAR();
  }

  #pragma unroll
  for (int mi = 0; mi < 8; ++mi) {
    #pragma unroll
    for (int r = 0; r < 4; ++r) {
      int row = m0 + wm * 128 + mi * 16 + lg * 4 + r;
      OT* crow = C + (size_t)row * N + n0 + wn * 64 + l15;
      #pragma unroll
      for (int ni = 0; ni < 4; ++ni) crow[ni * 16] = (OT)acc[mi][ni][r];
    }
  }
}

// ---- small GEMM (m97 128^2): C(MxN,OT) = A(MxK) * Bt(NxK)^T -----------------
template<typename OT>
__global__ __launch_bounds__(256) void gemm_bf16(
    const bf16* __restrict__ A, const bf16* __restrict__ Bt, OT* __restrict__ C,
    int M, int N, int K) {
  __shared__ alignas(16) bf16 As[128 * 64];
  __shared__ alignas(16) bf16 Bs[128 * 64];
  int tid = threadIdx.x;
  int w = tid >> 6, l = tid & 63;
  int l15 = l & 15, lg = l >> 4;
  int m0 = blockIdx.y * 128;
  int n0 = blockIdx.x * 128;
  int wr = (w >> 1) * 64, wc = (w & 1) * 64;
  f32x4 acc[4][4] = {};
  const size_t aBase = (size_t)m0 * K;
  const size_t bBase = (size_t)n0 * K;
  int nk = K >> 6;
  for (int kt = 0; kt < nk; ++kt) {
    int k0 = kt << 6;
    #pragma unroll
    for (int it = 0; it < 4; ++it) {
      int c = it * 256 + tid;
      int row = c >> 3, c8 = c & 7;
      gld_lds16(&As[(size_t)(it * 256 + w * 64) * 8],
                A + aBase + (size_t)row * K + k0 + c8 * 8);
      gld_lds16(&Bs[(size_t)(it * 256 + w * 64) * 8],
                Bt + bBase + (size_t)row * K + k0 + c8 * 8);
    }
    __syncthreads();
    #pragma unroll
    for (int kk = 0; kk < 64; kk += 32) {
      bf16x8 a[4], b[4];
      #pragma unroll
      for (int i = 0; i < 4; ++i)
        a[i] = *reinterpret_cast<const bf16x8*>(&As[(wr + i * 16 + l15) * 64 + kk + lg * 8]);
      #pragma unroll
      for (int i = 0; i < 4; ++i)
        b[i] = *reinterpret_cast<const bf16x8*>(&Bs[(wc + i * 16 + l15) * 64 + kk + lg * 8]);
      #pragma unroll
      for (int mi = 0; mi < 4; ++mi)
        #pragma unroll
        for (int ni = 0; ni < 4; ++ni)
          acc[mi][ni] = __builtin_amdgcn_mfma_f32_16x16x32_bf16(a[mi], b[ni], acc[mi][ni], 0, 0, 0);
    }
    __syncthreads();
  }
  #pragma unroll
  for (int mi = 0; mi < 4; ++mi) {
    #pragma unroll
    for (int r = 0; r < 4; ++r) {
      int row = m0 + wr + mi * 16 + lg * 4 + r;
      OT* crow = C + (size_t)row * N + n0 + wc + l15;
      #pragma unroll
      for (int ni = 0; ni < 4; ++ni) crow[ni * 16] = (OT)acc[mi][ni][r];
    }
  }
}

// ------- RoPE apply + head-split for Q (scaled 0.125) and K (from bf16 qkv) ---
__global__ void rope_qk(const bf16* __restrict__ qkv, const float* __restrict__ tab,
                        bf16* __restrict__ Qb, bf16* __restrict__ Kb) {
  int idx = blockIdx.x * 256 + threadIdx.x;  // ((b*S+s)*16 + h)*32 + i
  int i = idx & 31;
  int h = (idx >> 5) & 15;
  int bs = idx >> 9;
  int s = bs & 4095;
  int b = bs >> 12;
  const bf16* row = qkv + (size_t)bs * 3072;
  bf16x2 q2 = *reinterpret_cast<const bf16x2*>(row + h * 64 + 2 * i);
  bf16x2 k2 = *reinterpret_cast<const bf16x2*>(row + 1024 + h * 64 + 2 * i);
  f32x2 cs = *reinterpret_cast<const f32x2*>(tab + s * 64 + 2 * i);
  float c = cs[0], sn = cs[1];
  float q0 = (float)q2[0], q1 = (float)q2[1];
  float k0 = (float)k2[0], k1 = (float)k2[1];
  size_t ob = (((size_t)(b * 16 + h) * 4096) + s) * 64 + 2 * i;
  bf16x2 qo, ko;
  qo[0] = (bf16)((q0 * c - q1 * sn) * 0.125f);
  qo[1] = (bf16)((q0 * sn + q1 * c) * 0.125f);
  ko[0] = (bf16)(k0 * c - k1 * sn);
  ko[1] = (bf16)(k0 * sn + k1 * c);
  *reinterpret_cast<bf16x2*>(Qb + ob) = qo;
  *reinterpret_cast<bf16x2*>(Kb + ob) = ko;
}

// ---- K reshape (optional) + V transpose from bf16 source ----
__global__ void kv_post(const bf16* __restrict__ kv, bf16* __restrict__ Kdst,
                        bf16* __restrict__ Vt, int Lk, int rs, int koff, int voff) {
  __shared__ float t[64][65];
  int s0 = blockIdx.x * 64;
  int h = blockIdx.y, b = blockIdx.z;
  int tid = threadIdx.x;
  int lane_d = tid & 63;
  int rq = tid >> 6;
  const bf16* base = kv + (size_t)b * Lk * rs;
  if (Kdst) {
    #pragma unroll
    for (int r = 0; r < 16; ++r) {
      int si = r * 4 + rq;
      Kdst[(((size_t)(b * 16 + h) * Lk) + s0 + si) * 64 + lane_d] =
          base[(size_t)(s0 + si) * rs + koff + h * 64 + lane_d];
    }
  }
  #pragma unroll
  for (int r = 0; r < 16; ++r) {
    int si = r * 4 + rq;
    t[si][lane_d] = (float)base[(size_t)(s0 + si) * rs + voff + h * 64 + lane_d];
  }
  __syncthreads();
  #pragma unroll
  for (int r = 0; r < 16; ++r) {
    int d = r * 4 + rq;
    Vt[(((size_t)(b * 16 + h) * 64) + d) * Lk + s0 + lane_d] = (bf16)t[lane_d][d];
  }
}

// ---------------- flash attention (64-query tile, 4 waves x 16 q) -------------
template<bool WINDOWED>
__global__ __launch_bounds__(256) void attn_kernel(
    const bf16* __restrict__ Qb, const bf16* __restrict__ Kb, const bf16* __restrict__ Vt,
    bf16* __restrict__ outc, int S, int Lk, int col_off) {
  __shared__ alignas(16) bf16 Ks[64 * 64];
  __shared__ alignas(16) bf16 Vs[64 * 64];
  __shared__ alignas(16) bf16 Ps[4][16 * 72];
  int tid = threadIdx.x;
  int w = tid >> 6, l = tid & 63;
  int l15 = l & 15, lg = l >> 4;
  int qt = blockIdx.x, h = blockIdx.y, b = blockIdx.z;

  size_t qrow = (((size_t)(b * 16 + h) * S) + qt * 64 + w * 16 + l15) * 64;
  bf16x8 qf[2];
  qf[0] = *reinterpret_cast<const bf16x8*>(Qb + qrow + lg * 8);
  qf[1] = *reinterpret_cast<const bf16x8*>(Qb + qrow + 32 + lg * 8);
  const bf16* Kbase = Kb + ((size_t)(b * 16 + h) * Lk) * 64;
  const bf16* Vbase = Vt + ((size_t)(b * 16 + h) * 64) * Lk;

  float mrow = -1e30f, lsum = 0.f;
  f32x4 acc[4] = {};

  int kt_hi, kt_lo;
  if (WINDOWED) { kt_hi = qt; kt_lo = qt >= 8 ? qt - 8 : 0; }
  else          { kt_hi = (Lk >> 6) - 1; kt_lo = 0; }

  for (int kt = kt_hi; kt >= kt_lo; --kt) {
    const bf16* kg = Kbase + (size_t)kt * 64 * 64;
    #pragma unroll
    for (int it = 0; it < 2; ++it)
      gld_lds16(&Ks[(it * 256 + w * 64) * 8], kg + (size_t)(it * 256 + tid) * 8);
    #pragma unroll
    for (int it = 0; it < 2; ++it) {
      int c = it * 256 + tid;
      int row = c >> 3, c8 = c & 7;
      gld_lds16(&Vs[(it * 256 + w * 64) * 8],
                Vbase + (size_t)row * Lk + kt * 64 + c8 * 8);
    }
    __syncthreads();

    f32x4 st[4] = {};
    #pragma unroll
    for (int kk = 0; kk < 2; ++kk) {
      #pragma unroll
      for (int f = 0; f < 4; ++f) {
        bf16x8 kf = *reinterpret_cast<const bf16x8*>(&Ks[(f * 16 + l15) * 64 + kk * 32 + lg * 8]);
        st[f] = __builtin_amdgcn_mfma_f32_16x16x32_bf16(kf, qf[kk], st[f], 0, 0, 0);
      }
    }

    if (WINDOWED) {
      int qi = w * 16 + l15;
      if (kt == qt) {
        #pragma unroll
        for (int f = 0; f < 4; ++f)
          #pragma unroll
          for (int r = 0; r < 4; ++r)
            if (f * 16 + lg * 4 + r > qi) st[f][r] = -1e30f;
      } else if (kt == qt - 8) {
        #pragma unroll
        for (int f = 0; f < 4; ++f)
          #pragma unroll
          for (int r = 0; r < 4; ++r)
            if (f * 16 + lg * 4 + r <= qi) st[f][r] = -1e30f;
      }
    }

    float rm = -1e30f;
    #pragma unroll
    for (int f = 0; f < 4; ++f)
      #pragma unroll
      for (int r = 0; r < 4; ++r) rm = fmaxf(rm, st[f][r]);
    rm = fmaxf(rm, __shfl_xor(rm, 16));
    rm = fmaxf(rm, __shfl_xor(rm, 32));
    float mnew = fmaxf(mrow, rm);
    float fsc = __expf(mrow - mnew);
    float ps = 0.f;
    bf16x4 pv[4];
    #pragma unroll
    for (int f = 0; f < 4; ++f)
      #pragma unroll
      for (int r = 0; r < 4; ++r) {
        float p = __expf(st[f][r] - mnew);
        ps += p;
        pv[f][r] = (bf16)p;
      }
    ps += __shfl_xor(ps, 16);
    ps += __shfl_xor(ps, 32);
    lsum = lsum * fsc + ps;
    mrow = mnew;

    #pragma unroll
    for (int f = 0; f < 4; ++f)
      *reinterpret_cast<bf16x4*>(&Ps[w][l15 * 72 + f * 16 + lg * 4]) = pv[f];

    #pragma unroll
    for (int r = 0; r < 4; ++r) {
      float fr = __shfl(fsc, lg * 4 + r);
      #pragma unroll
      for (int f = 0; f < 4; ++f) acc[f][r] *= fr;
    }

    #pragma unroll
    for (int kk = 0; kk < 2; ++kk) {
      bf16x8 pa = *reinterpret_cast<const bf16x8*>(&Ps[w][l15 * 72 + kk * 32 + lg * 8]);
      #pragma unroll
      for (int f = 0; f < 4; ++f) {
        bf16x8 vf = *reinterpret_cast<const bf16x8*>(&Vs[(f * 16 + l15) * 64 + kk * 32 + lg * 8]);
        acc[f] = __builtin_amdgcn_mfma_f32_16x16x32_bf16(pa, vf, acc[f], 0, 0, 0);
      }
    }
    __syncthreads();
  }

  float inv = 1.f / lsum;
  #pragma unroll
  for (int r = 0; r < 4; ++r) {
    float ir = __shfl(inv, lg * 4 + r);
    int srow = qt * 64 + w * 16 + lg * 4 + r;
    bf16* orow = outc + ((size_t)b * S + srow) * 3072 + col_off + h * 64 + l15;
    #pragma unroll
    for (int f = 0; f < 4; ++f) orow[f * 16] = (bf16)(acc[f][r] * ir);
  }
}

// ------------- RMSNorm in-place per (token, 1024-segment), bf16 ---------------
__global__ __launch_bounds__(256) void rmsnorm_kernel(
    bf16* data, const float* __restrict__ g0,
    const float* __restrict__ g1, const float* __restrict__ g2) {
  int token = blockIdx.x;
  int seg = blockIdx.y;
  const float* g = seg == 0 ? g0 : (seg == 1 ? g1 : g2);
  int tid = threadIdx.x;
  size_t base = (size_t)token * 3072 + seg * 1024;
  bf16x4 bv = reinterpret_cast<const bf16x4*>(data + base)[tid];
  f32x4 v;
  #pragma unroll
  for (int j = 0; j < 4; ++j) v[j] = (float)bv[j];
  float ss = v[0] * v[0] + v[1] * v[1] + v[2] * v[2] + v[3] * v[3];
  #pragma unroll
  for (int m = 1; m < 64; m <<= 1) ss += __shfl_xor(ss, m);
  __shared__ float red[4];
  if ((tid & 63) == 0) red[tid >> 6] = ss;
  __syncthreads();
  float tot = red[0] + red[1] + red[2] + red[3];
  float sc = rsqrtf(tot * (1.f / 1024.f) + 1.19209290e-07f);
  f32x4 gv = reinterpret_cast<const f32x4*>(g)[tid];
  bf16x4 o;
  #pragma unroll
  for (int j = 0; j < 4; ++j) o[j] = (bf16)(v[j] * sc * gv[j]);
  reinterpret_cast<bf16x4*>(data + base)[tid] = o;
}

// -------- silu(gate)*value : gv (8192x2048) bf16 -> (8192x1024) bf16 ----------
__global__ void silu_kernel(const bf16* __restrict__ gv, bf16* __restrict__ out) {
  int T = blockIdx.x * 256 + threadIdx.x;
  int row = T >> 8, c4 = (T & 255) * 4;
  bf16x4 g = *reinterpret_cast<const bf16x4*>(gv + (size_t)row * 2048 + c4);
  bf16x4 vv = *reinterpret_cast<const bf16x4*>(gv + (size_t)row * 2048 + 1024 + c4);
  bf16x4 o;
  #pragma unroll
  for (int j = 0; j < 4; ++j) {
    float x = (float)g[j];
    o[j] = (bf16)((x / (1.f + __expf(-x))) * (float)vv[j]);
  }
  *reinterpret_cast<bf16x4*>(out + (size_t)row * 1024 + c4) = o;
}

// =============================== launch ======================================
extern "C" void kernel_launch(void* const* d_in, const int* in_sizes, int n_in,
                              void* d_out, int out_size, void* d_ws, size_t ws_size,
                              hipStream_t stream) {
  (void)in_sizes; (void)n_in; (void)out_size; (void)ws_size;
  const float* x       = (const float*)d_in[0];
  const float* lm      = (const float*)d_in[1];
  const float* arch    = (const float*)d_in[2];
  const float* W_qkv   = (const float*)d_in[3];
  const float* W_lm    = (const float*)d_in[4];
  const float* W_arch  = (const float*)d_in[5];
  const float* W_o     = (const float*)d_in[6];
  const float* W_gate  = (const float*)d_in[7];
  const float* g_local = (const float*)d_in[8];
  const float* g_lm    = (const float*)d_in[9];
  const float* g_arch  = (const float*)d_in[10];
  float* out = (float*)d_out;

  char* ws = (char*)d_ws;
  size_t off = 0;
  auto alloc = [&](size_t bytes) -> void* {
    void* p = ws + off;
    off += (bytes + 255) & ~(size_t)255;
    return p;
  };
  // persistent
  bf16*  Wqkv_t   = (bf16*) alloc(3072ull * 1024 * 2);
  bf16*  Wlm_t    = (bf16*) alloc(2048ull * 1024 * 2);
  bf16*  Warch_t  = (bf16*) alloc(2048ull * 1024 * 2);
  bf16*  Wgate_t  = (bf16*) alloc(2048ull * 3072 * 2);
  bf16*  Wo_t     = (bf16*) alloc(1024ull * 1024 * 2);
  bf16*  lm_bf    = (bf16*) alloc(512ull * 1024 * 2);
  bf16*  arch_bf  = (bf16*) alloc(256ull * 1024 * 2);
  float* ropetab  = (float*)alloc(4096ull * 64 * 4);
  bf16*  Klm      = (bf16*) alloc(2ull * 16 * 256 * 64 * 2);
  bf16*  Vlm_t    = (bf16*) alloc(2ull * 16 * 64 * 256 * 2);
  bf16*  Ka       = (bf16*) alloc(2ull * 16 * 128 * 64 * 2);
  bf16*  Va_t     = (bf16*) alloc(2ull * 16 * 64 * 128 * 2);
  bf16*  lmkv_bf  = (bf16*) alloc(512ull * 2048 * 2);
  bf16*  akv_bf   = (bf16*) alloc(256ull * 2048 * 2);
  // region 1 (16 MB): x_bf, later gated
  char* R1 = (char*)alloc(8192ull * 1024 * 2);
  bf16* x_bf  = (bf16*)R1;
  bf16* gated = (bf16*)R1;
  // region 2 (48 MB): qkv_bf, later concat (bf16)
  char* R2 = (char*)alloc(8192ull * 3072 * 2);
  bf16* qkv_bf  = (bf16*)R2;
  bf16* concatb = (bf16*)R2;
  // region 3 (48 MB): Qb+Kb+Vt, later gate-GEMM output (32 MB)
  char* R3 = (char*)alloc(3ull * 16 * 1024 * 1024);
  bf16* Qb = (bf16*)R3;
  bf16* Kb = (bf16*)(R3 + 16ull * 1024 * 1024);
  bf16* Vt = (bf16*)(R3 + 32ull * 1024 * 1024);
  bf16* gv = (bf16*)R3;

  // 1. weight transposes + input casts + rope table
  transpose_cast<<<dim3(96, 32), dim3(32, 8), 0, stream>>>(W_qkv, Wqkv_t, 1024, 3072);
  transpose_cast<<<dim3(64, 32), dim3(32, 8), 0, stream>>>(W_lm, Wlm_t, 1024, 2048);
  transpose_cast<<<dim3(64, 32), dim3(32, 8), 0, stream>>>(W_arch, Warch_t, 1024, 2048);
  transpose_cast<<<dim3(64, 96), dim3(32, 8), 0, stream>>>(W_gate, Wgate_t, 3072, 2048);
  transpose_cast<<<dim3(32, 32), dim3(32, 8), 0, stream>>>(W_o, Wo_t, 1024, 1024);
  cast_f32_bf16<<<8192, 256, 0, stream>>>(x, x_bf, 8192 * 1024 / 4);
  cast_f32_bf16<<<512, 256, 0, stream>>>(lm, lm_bf, 512 * 1024 / 4);
  cast_f32_bf16<<<256, 256, 0, stream>>>(arch, arch_bf, 256 * 1024 / 4);
  rope_table<<<512, 256, 0, stream>>>(ropetab);

  // 2. projection GEMMs
  gemm256<bf16><<<32 * 12, 512, 0, stream>>>(x_bf, Wqkv_t, qkv_bf, 8192, 3072, 1024);
  gemm_bf16<bf16><<<dim3(16, 4), 256, 0, stream>>>(lm_bf, Wlm_t, lmkv_bf, 512, 2048, 1024);
  gemm_bf16<bf16><<<dim3(16, 2), 256, 0, stream>>>(arch_bf, Warch_t, akv_bf, 256, 2048, 1024);

  // 3. rope + head-split + V transposes
  rope_qk<<<16384, 256, 0, stream>>>(qkv_bf, ropetab, Qb, Kb);
  kv_post<<<dim3(64, 16, 2), 256, 0, stream>>>(qkv_bf, nullptr, Vt, 4096, 3072, 0, 2048);
  kv_post<<<dim3(4, 16, 2), 256, 0, stream>>>(lmkv_bf, Klm, Vlm_t, 256, 2048, 0, 1024);
  kv_post<<<dim3(2, 16, 2), 256, 0, stream>>>(akv_bf, Ka, Va_t, 128, 2048, 0, 1024);

  // 4. attentions -> concat
  attn_kernel<true><<<dim3(64, 16, 2), 256, 0, stream>>>(Qb, Kb, Vt, concatb, 4096, 4096, 0);
  attn_kernel<false><<<dim3(64, 16, 2), 256, 0, stream>>>(Qb, Klm, Vlm_t, concatb, 4096, 256, 1024);
  attn_kernel<false><<<dim3(64, 16, 2), 256, 0, stream>>>(Qb, Ka, Va_t, concatb, 4096, 128, 2048);

  // 5. per-branch RMSNorm in place
  rmsnorm_kernel<<<dim3(8192, 3), 256, 0, stream>>>(concatb, g_local, g_lm, g_arch);

  // 6. gate GEMM + silu + output GEMM
  gemm256<bf16><<<32 * 8, 512, 0, stream>>>(concatb, Wgate_t, gv, 8192, 2048, 3072);
  silu_kernel<<<8192, 256, 0, stream>>>(gv, gated);
  gemm256<float><<<32 * 4, 512, 0, stream>>>(gated, Wo_t, out, 8192, 1024, 1024);
}

// Round 4
// 417.595 us; speedup vs baseline: 1.1737x; 1.0448x over previous
//
#include <hip/hip_runtime.h>
#include <cstdint>
#include <cstddef>

typedef __bf16 bf16;
typedef __bf16 bf16x2 __attribute__((ext_vector_type(2)));
typedef __bf16 bf16x4 __attribute__((ext_vector_type(4)));
typedef __bf16 bf16x8 __attribute__((ext_vector_type(8)));
typedef float  f32x2 __attribute__((ext_vector_type(2)));
typedef float  f32x4 __attribute__((ext_vector_type(4)));

#define DEVFN __device__ __forceinline__
#define BAR()  asm volatile("s_barrier" ::: "memory")
#define VMW0() asm volatile("s_waitcnt vmcnt(0)" ::: "memory")
#define VMW3() asm volatile("s_waitcnt vmcnt(3)" ::: "memory")
#define VMW4() asm volatile("s_waitcnt vmcnt(4)" ::: "memory")

// async global->LDS, 16B per lane; LDS dest = wave-uniform base + lane*16
DEVFN void gld_lds16(void* lds, const void* g) {
  __builtin_amdgcn_global_load_lds(
      (__attribute__((address_space(1))) void*)g,
      (__attribute__((address_space(3))) void*)lds,
      16, 0, 0);
}

// ---------------- elementwise cast f32 -> bf16 (vectorized x4) ----------------
__global__ void cast_f32_bf16(const float* __restrict__ in, bf16* __restrict__ out, int n4) {
  int i = blockIdx.x * blockDim.x + threadIdx.x;
  if (i < n4) {
    f32x4 v = reinterpret_cast<const f32x4*>(in)[i];
    bf16x4 o;
    o[0] = (bf16)v[0]; o[1] = (bf16)v[1]; o[2] = (bf16)v[2]; o[3] = (bf16)v[3];
    reinterpret_cast<bf16x4*>(out)[i] = o;
  }
}

// ---------------- transpose + cast: in (R x C) f32 -> out (C x R) bf16 --------
__global__ void transpose_cast(const float* __restrict__ in, bf16* __restrict__ out,
                               int R, int C) {
  __shared__ float t[32][33];
  int tx = threadIdx.x, ty = threadIdx.y;
  int c = blockIdx.x * 32 + tx;
  #pragma unroll
  for (int j = 0; j < 4; ++j) {
    int r = blockIdx.y * 32 + ty + j * 8;
    t[ty + j * 8][tx] = in[(size_t)r * C + c];
  }
  __syncthreads();
  int rr = blockIdx.y * 32 + tx;
  #pragma unroll
  for (int j = 0; j < 4; ++j) {
    int cc = blockIdx.x * 32 + ty + j * 8;
    out[(size_t)cc * R + rr] = (bf16)t[tx][ty + j * 8];
  }
}

// ---------------- RoPE cos/sin table: tab[s*64 + 2i]=cos, +1=sin --------------
__global__ void rope_table(float* __restrict__ tab) {
  int idx = blockIdx.x * 256 + threadIdx.x;   // s*32 + i, s<4096, i<32
  int s = idx >> 5, i = idx & 31;
  float theta = powf(10000.f, -(float)(2 * i) * (1.f / 64.f));
  float f = (float)s * theta;
  tab[idx * 2]     = cosf(f);
  tab[idx * 2 + 1] = sinf(f);
}

// ====================== 256x256 8-wave deep-pipelined GEMM ====================
// C(MxN,OT) = A(MxK,bf16) * Bt(NxK,bf16)^T. M,N mult of 256, K of 64.
// grid 1-D, divisible by 8. 512 threads. LDS 128 KiB double-buffered.
// 4 phases/K-tile, counted vmcnt(4) (vmcnt(0) on last tile), A-hi frag reads
// hoisted into the MFMA shadow of P0/P2.
template<typename OT>
__global__ __launch_bounds__(512) void gemm256(
    const bf16* __restrict__ A, const bf16* __restrict__ Bt, OT* __restrict__ C,
    int M, int N, int K) {
  __shared__ alignas(16) bf16 lds[2][2][2][256 * 32];
  const int tid = threadIdx.x;
  const int w = tid >> 6, l = tid & 63;
  const int l15 = l & 15, lg = l >> 4;
  const int wm = w >> 2, wn = w & 3;
  const int nwg = gridDim.x, qx = nwg >> 3;
  const int swz = (blockIdx.x & 7) * qx + (blockIdx.x >> 3);
  const int gx = N >> 8;
  const int m0 = (swz / gx) << 8;
  const int n0 = (swz % gx) << 8;
  const int nt = K >> 6;

  auto stage = [&](int b, int ab, int kk, int t) {
    const bf16* __restrict__ src = ab ? Bt : A;
    const int base0 = ab ? n0 : m0;
    const int k0 = (t << 6) + (kk << 5);
    #pragma unroll
    for (int i = 0; i < 2; ++i) {
      int u = i * 512 + tid;
      int row = u >> 2, slot = u & 3;
      int sslot = slot ^ ((row >> 1) & 3);
      gld_lds16(&lds[b][ab][kk][(i * 512 + w * 64) * 8],
                src + (size_t)(base0 + row) * K + k0 + sslot * 8);
    }
  };
  auto rd = [&](int b, int ab, int kk, int r) -> bf16x8 {
    return *reinterpret_cast<const bf16x8*>(
        &lds[b][ab][kk][(r << 5) + ((lg ^ ((r >> 1) & 3)) << 3)]);
  };

  f32x4 acc[8][4] = {};
  bf16x8 aLo[4], aHi[4], bfr[4];

  stage(0, 0, 0, 0);
  stage(0, 1, 0, 0);
  stage(0, 0, 1, 0);
  stage(0, 1, 1, 0);
  VMW4();
  BAR();

  for (int t = 0; t < nt; ++t) {
    const int c = t & 1;
    const bool st = (t + 1) < nt;
    // ---- P0: kk=0, M-frags 0-3 ----
    #pragma unroll
    for (int f = 0; f < 4; ++f) aLo[f] = rd(c, 0, 0, wm * 128 + f * 16 + l15);
    #pragma unroll
    for (int f = 0; f < 4; ++f) bfr[f] = rd(c, 1, 0, wn * 64 + f * 16 + l15);
    if (st) stage(c ^ 1, 0, 0, t + 1);
    BAR();
    __builtin_amdgcn_s_setprio(1);
    #pragma unroll
    for (int mi = 0; mi < 4; ++mi)
      #pragma unroll
      for (int ni = 0; ni < 4; ++ni)
        acc[mi][ni] = __builtin_amdgcn_mfma_f32_16x16x32_bf16(aLo[mi], bfr[ni], acc[mi][ni], 0, 0, 0);
    __builtin_amdgcn_s_setprio(0);
    #pragma unroll
    for (int f = 0; f < 4; ++f) aHi[f] = rd(c, 0, 0, wm * 128 + (f + 4) * 16 + l15);
    BAR();
    // ---- P1: kk=0, M-frags 4-7 ----
    if (st) stage(c ^ 1, 1, 0, t + 1);
    BAR();
    __builtin_amdgcn_s_setprio(1);
    #pragma unroll
    for (int mi = 0; mi < 4; ++mi)
      #pragma unroll
      for (int ni = 0; ni < 4; ++ni)
        acc[mi + 4][ni] = __builtin_amdgcn_mfma_f32_16x16x32_bf16(aHi[mi], bfr[ni], acc[mi + 4][ni], 0, 0, 0);
    __builtin_amdgcn_s_setprio(0);
    if (st) { VMW4(); } else { VMW0(); }   // kk1(t) landed for P2/P3
    BAR();
    // ---- P2: kk=1, M-frags 0-3 ----
    #pragma unroll
    for (int f = 0; f < 4; ++f) aLo[f] = rd(c, 0, 1, wm * 128 + f * 16 + l15);
    #pragma unroll
    for (int f = 0; f < 4; ++f) bfr[f] = rd(c, 1, 1, wn * 64 + f * 16 + l15);
    if (st) stage(c ^ 1, 0, 1, t + 1);
    BAR();
    __builtin_amdgcn_s_setprio(1);
    #pragma unroll
    for (int mi = 0; mi < 4; ++mi)
      #pragma unroll
      for (int ni = 0; ni < 4; ++ni)
        acc[mi][ni] = __builtin_amdgcn_mfma_f32_16x16x32_bf16(aLo[mi], bfr[ni], acc[mi][ni], 0, 0, 0);
    __builtin_amdgcn_s_setprio(0);
    #pragma unroll
    for (int f = 0; f < 4; ++f) aHi[f] = rd(c, 0, 1, wm * 128 + (f + 4) * 16 + l15);
    BAR();
    // ---- P3: kk=1, M-frags 4-7 ----
    if (st) stage(c ^ 1, 1, 1, t + 1);
    BAR();
    __builtin_amdgcn_s_setprio(1);
    #pragma unroll
    for (int mi = 0; mi < 4; ++mi)
      #pragma unroll
      for (int ni = 0; ni < 4; ++ni)
        acc[mi + 4][ni] = __builtin_amdgcn_mfma_f32_16x16x32_bf16(aHi[mi], bfr[ni], acc[mi + 4][ni], 0, 0, 0);
    __builtin_amdgcn_s_setprio(0);
    VMW4();               // st: drains kk0(t+1); last tile: no-op (0 in flight)
    BAR();
  }

  #pragma unroll
  for (int mi = 0; mi < 8; ++mi) {
    #pragma unroll
    for (int r = 0; r < 4; ++r) {
      int row = m0 + wm * 128 + mi * 16 + lg * 4 + r;
      OT* crow = C + (size_t)row * N + n0 + wn * 64 + l15;
      #pragma unroll
      for (int ni = 0; ni < 4; ++ni) crow[ni * 16] = (OT)acc[mi][ni][r];
    }
  }
}

// ============== 256x128-tile variant (grid quantization helper) ==============
// waves 4M x 2N (per-wave 64x64). 2 phases/K-tile, counted vmcnt(3). 96 KiB LDS.
template<typename OT>
__global__ __launch_bounds__(512) void gemm256n128(
    const bf16* __restrict__ A, const bf16* __restrict__ Bt, OT* __restrict__ C,
    int M, int N, int K) {
  __shared__ alignas(16) bf16 ldsA[2][2][256 * 32];
  __shared__ alignas(16) bf16 ldsB[2][2][128 * 32];
  const int tid = threadIdx.x;
  const int w = tid >> 6, l = tid & 63;
  const int l15 = l & 15, lg = l >> 4;
  const int wm = w >> 1, wn = w & 1;
  const int nwg = gridDim.x, qx = nwg >> 3;
  const int swz = (blockIdx.x & 7) * qx + (blockIdx.x >> 3);
  const int gx = N >> 7;
  const int m0 = (swz / gx) << 8;
  const int n0 = (swz % gx) << 7;
  const int nt = K >> 6;

  auto stageA = [&](int b, int kk, int t) {
    const int k0 = (t << 6) + (kk << 5);
    #pragma unroll
    for (int i = 0; i < 2; ++i) {
      int u = i * 512 + tid;
      int row = u >> 2, slot = u & 3;
      int ss = slot ^ ((row >> 1) & 3);
      gld_lds16(&ldsA[b][kk][(i * 512 + w * 64) * 8],
                A + (size_t)(m0 + row) * K + k0 + ss * 8);
    }
  };
  auto stageB = [&](int b, int kk, int t) {
    const int k0 = (t << 6) + (kk << 5);
    int row = tid >> 2, slot = tid & 3;
    int ss = slot ^ ((row >> 1) & 3);
    gld_lds16(&ldsB[b][kk][(w * 64) * 8],
              Bt + (size_t)(n0 + row) * K + k0 + ss * 8);
  };
  auto rdA = [&](int b, int kk, int r) -> bf16x8 {
    return *reinterpret_cast<const bf16x8*>(
        &ldsA[b][kk][(r << 5) + ((lg ^ ((r >> 1) & 3)) << 3)]);
  };
  auto rdB = [&](int b, int kk, int r) -> bf16x8 {
    return *reinterpret_cast<const bf16x8*>(
        &ldsB[b][kk][(r << 5) + ((lg ^ ((r >> 1) & 3)) << 3)]);
  };

  f32x4 acc[4][4] = {};
  bf16x8 af[4], bf[4];

  stageA(0, 0, 0); stageB(0, 0, 0);
  stageA(0, 1, 0); stageB(0, 1, 0);
  VMW3();
  BAR();

  for (int t = 0; t < nt; ++t) {
    const int c = t & 1;
    const bool st = (t + 1) < nt;
    #pragma unroll
    for (int kk = 0; kk < 2; ++kk) {
      #pragma unroll
      for (int f = 0; f < 4; ++f) af[f] = rdA(c, kk, wm * 64 + f * 16 + l15);
      #pragma unroll
      for (int f = 0; f < 4; ++f) bf[f] = rdB(c, kk, wn * 64 + f * 16 + l15);
      if (st) { stageA(c ^ 1, kk, t + 1); stageB(c ^ 1, kk, t + 1); }
      BAR();
      __builtin_amdgcn_s_setprio(1);
      #pragma unroll
      for (int mi = 0; mi < 4; ++mi)
        #pragma unroll
        for (int ni = 0; ni < 4; ++ni)
          acc[mi][ni] = __builtin_amdgcn_mfma_f32_16x16x32_bf16(af[mi], bf[ni], acc[mi][ni], 0, 0, 0);
      __builtin_amdgcn_s_setprio(0);
      if (st) { VMW3(); } else if (kk == 0) { VMW0(); }
      BAR();
    }
  }

  #pragma unroll
  for (int mi = 0; mi < 4; ++mi) {
    #pragma unroll
    for (int r = 0; r < 4; ++r) {
      int row = m0 + wm * 64 + mi * 16 + lg * 4 + r;
      OT* crow = C + (size_t)row * N + n0 + wn * 64 + l15;
      #pragma unroll
      for (int ni = 0; ni < 4; ++ni) crow[ni * 16] = (OT)acc[mi][ni][r];
    }
  }
}

// ---- small GEMM (m97 128^2): C(MxN,OT) = A(MxK) * Bt(NxK)^T -----------------
template<typename OT>
__global__ __launch_bounds__(256) void gemm_bf16(
    const bf16* __restrict__ A, const bf16* __restrict__ Bt, OT* __restrict__ C,
    int M, int N, int K) {
  __shared__ alignas(16) bf16 As[128 * 64];
  __shared__ alignas(16) bf16 Bs[128 * 64];
  int tid = threadIdx.x;
  int w = tid >> 6, l = tid & 63;
  int l15 = l & 15, lg = l >> 4;
  int m0 = blockIdx.y * 128;
  int n0 = blockIdx.x * 128;
  int wr = (w >> 1) * 64, wc = (w & 1) * 64;
  f32x4 acc[4][4] = {};
  const size_t aBase = (size_t)m0 * K;
  const size_t bBase = (size_t)n0 * K;
  int nk = K >> 6;
  for (int kt = 0; kt < nk; ++kt) {
    int k0 = kt << 6;
    #pragma unroll
    for (int it = 0; it < 4; ++it) {
      int c = it * 256 + tid;
      int row = c >> 3, c8 = c & 7;
      gld_lds16(&As[(size_t)(it * 256 + w * 64) * 8],
                A + aBase + (size_t)row * K + k0 + c8 * 8);
      gld_lds16(&Bs[(size_t)(it * 256 + w * 64) * 8],
                Bt + bBase + (size_t)row * K + k0 + c8 * 8);
    }
    __syncthreads();
    #pragma unroll
    for (int kk = 0; kk < 64; kk += 32) {
      bf16x8 a[4], b[4];
      #pragma unroll
      for (int i = 0; i < 4; ++i)
        a[i] = *reinterpret_cast<const bf16x8*>(&As[(wr + i * 16 + l15) * 64 + kk + lg * 8]);
      #pragma unroll
      for (int i = 0; i < 4; ++i)
        b[i] = *reinterpret_cast<const bf16x8*>(&Bs[(wc + i * 16 + l15) * 64 + kk + lg * 8]);
      #pragma unroll
      for (int mi = 0; mi < 4; ++mi)
        #pragma unroll
        for (int ni = 0; ni < 4; ++ni)
          acc[mi][ni] = __builtin_amdgcn_mfma_f32_16x16x32_bf16(a[mi], b[ni], acc[mi][ni], 0, 0, 0);
    }
    __syncthreads();
  }
  #pragma unroll
  for (int mi = 0; mi < 4; ++mi) {
    #pragma unroll
    for (int r = 0; r < 4; ++r) {
      int row = m0 + wr + mi * 16 + lg * 4 + r;
      OT* crow = C + (size_t)row * N + n0 + wc + l15;
      #pragma unroll
      for (int ni = 0; ni < 4; ++ni) crow[ni * 16] = (OT)acc[mi][ni][r];
    }
  }
}

// ------- RoPE apply + head-split for Q (scaled 0.125) and K (from bf16 qkv) ---
__global__ void rope_qk(const bf16* __restrict__ qkv, const float* __restrict__ tab,
                        bf16* __restrict__ Qb, bf16* __restrict__ Kb) {
  int idx = blockIdx.x * 256 + threadIdx.x;  // ((b*S+s)*16 + h)*32 + i
  int i = idx & 31;
  int h = (idx >> 5) & 15;
  int bs = idx >> 9;
  int s = bs & 4095;
  int b = bs >> 12;
  const bf16* row = qkv + (size_t)bs * 3072;
  bf16x2 q2 = *reinterpret_cast<const bf16x2*>(row + h * 64 + 2 * i);
  bf16x2 k2 = *reinterpret_cast<const bf16x2*>(row + 1024 + h * 64 + 2 * i);
  f32x2 cs = *reinterpret_cast<const f32x2*>(tab + s * 64 + 2 * i);
  float c = cs[0], sn = cs[1];
  float q0 = (float)q2[0], q1 = (float)q2[1];
  float k0 = (float)k2[0], k1 = (float)k2[1];
  size_t ob = (((size_t)(b * 16 + h) * 4096) + s) * 64 + 2 * i;
  bf16x2 qo, ko;
  qo[0] = (bf16)((q0 * c - q1 * sn) * 0.125f);
  qo[1] = (bf16)((q0 * sn + q1 * c) * 0.125f);
  ko[0] = (bf16)(k0 * c - k1 * sn);
  ko[1] = (bf16)(k0 * sn + k1 * c);
  *reinterpret_cast<bf16x2*>(Qb + ob) = qo;
  *reinterpret_cast<bf16x2*>(Kb + ob) = ko;
}

// ---- K reshape (optional) + V transpose from bf16 source ----
__global__ void kv_post(const bf16* __restrict__ kv, bf16* __restrict__ Kdst,
                        bf16* __restrict__ Vt, int Lk, int rs, int koff, int voff) {
  __shared__ float t[64][65];
  int s0 = blockIdx.x * 64;
  int h = blockIdx.y, b = blockIdx.z;
  int tid = threadIdx.x;
  int lane_d = tid & 63;
  int rq = tid >> 6;
  const bf16* base = kv + (size_t)b * Lk * rs;
  if (Kdst) {
    #pragma unroll
    for (int r = 0; r < 16; ++r) {
      int si = r * 4 + rq;
      Kdst[(((size_t)(b * 16 + h) * Lk) + s0 + si) * 64 + lane_d] =
          base[(size_t)(s0 + si) * rs + koff + h * 64 + lane_d];
    }
  }
  #pragma unroll
  for (int r = 0; r < 16; ++r) {
    int si = r * 4 + rq;
    t[si][lane_d] = (float)base[(size_t)(s0 + si) * rs + voff + h * 64 + lane_d];
  }
  __syncthreads();
  #pragma unroll
  for (int r = 0; r < 16; ++r) {
    int d = r * 4 + rq;
    Vt[(((size_t)(b * 16 + h) * 64) + d) * Lk + s0 + lane_d] = (bf16)t[lane_d][d];
  }
}

// ---------------- flash attention (64-query tile, 4 waves x 16 q) -------------
// K/V tiles staged with 8-slot XOR swizzle (slot ^= row&7): pre-swizzled global
// source + linear LDS dest + swizzled ds_read (both-sides involution).
template<bool WINDOWED>
__global__ __launch_bounds__(256) void attn_kernel(
    const bf16* __restrict__ Qb, const bf16* __restrict__ Kb, const bf16* __restrict__ Vt,
    bf16* __restrict__ outc, int S, int Lk, int col_off) {
  __shared__ alignas(16) bf16 Ks[64 * 64];
  __shared__ alignas(16) bf16 Vs[64 * 64];
  __shared__ alignas(16) bf16 Ps[4][16 * 72];
  int tid = threadIdx.x;
  int w = tid >> 6, l = tid & 63;
  int l15 = l & 15, lg = l >> 4;
  int qt = blockIdx.x, h = blockIdx.y, b = blockIdx.z;

  size_t qrow = (((size_t)(b * 16 + h) * S) + qt * 64 + w * 16 + l15) * 64;
  bf16x8 qf[2];
  qf[0] = *reinterpret_cast<const bf16x8*>(Qb + qrow + lg * 8);
  qf[1] = *reinterpret_cast<const bf16x8*>(Qb + qrow + 32 + lg * 8);
  const bf16* Kbase = Kb + ((size_t)(b * 16 + h) * Lk) * 64;
  const bf16* Vbase = Vt + ((size_t)(b * 16 + h) * 64) * Lk;

  float mrow = -1e30f, lsum = 0.f;
  f32x4 acc[4] = {};

  int kt_hi, kt_lo;
  if (WINDOWED) { kt_hi = qt; kt_lo = qt >= 8 ? qt - 8 : 0; }
  else          { kt_hi = (Lk >> 6) - 1; kt_lo = 0; }

  for (int kt = kt_hi; kt >= kt_lo; --kt) {
    const bf16* kg = Kbase + (size_t)kt * 64 * 64;
    #pragma unroll
    for (int it = 0; it < 2; ++it) {
      int u = it * 256 + tid;
      int row = u >> 3, sl = u & 7;
      gld_lds16(&Ks[(it * 256 + w * 64) * 8], kg + row * 64 + (sl ^ (row & 7)) * 8);
    }
    #pragma unroll
    for (int it = 0; it < 2; ++it) {
      int u = it * 256 + tid;
      int row = u >> 3, sl = u & 7;
      gld_lds16(&Vs[(it * 256 + w * 64) * 8],
                Vbase + (size_t)row * Lk + kt * 64 + (sl ^ (row & 7)) * 8);
    }
    __syncthreads();

    f32x4 st[4] = {};
    #pragma unroll
    for (int kk = 0; kk < 2; ++kk) {
      #pragma unroll
      for (int f = 0; f < 4; ++f) {
        bf16x8 kf = *reinterpret_cast<const bf16x8*>(
            &Ks[(f * 16 + l15) * 64 + (((kk * 4 + lg) ^ (l15 & 7)) << 3)]);
        st[f] = __builtin_amdgcn_mfma_f32_16x16x32_bf16(kf, qf[kk], st[f], 0, 0, 0);
      }
    }

    if (WINDOWED) {
      int qi = w * 16 + l15;
      if (kt == qt) {
        #pragma unroll
        for (int f = 0; f < 4; ++f)
          #pragma unroll
          for (int r = 0; r < 4; ++r)
            if (f * 16 + lg * 4 + r > qi) st[f][r] = -1e30f;
      } else if (kt == qt - 8) {
        #pragma unroll
        for (int f = 0; f < 4; ++f)
          #pragma unroll
          for (int r = 0; r < 4; ++r)
            if (f * 16 + lg * 4 + r <= qi) st[f][r] = -1e30f;
      }
    }

    float rm = -1e30f;
    #pragma unroll
    for (int f = 0; f < 4; ++f)
      #pragma unroll
      for (int r = 0; r < 4; ++r) rm = fmaxf(rm, st[f][r]);
    rm = fmaxf(rm, __shfl_xor(rm, 16));
    rm = fmaxf(rm, __shfl_xor(rm, 32));
    float mnew = fmaxf(mrow, rm);
    float fsc = __expf(mrow - mnew);
    float ps = 0.f;
    bf16x4 pv[4];
    #pragma unroll
    for (int f = 0; f < 4; ++f)
      #pragma unroll
      for (int r = 0; r < 4; ++r) {
        float p = __expf(st[f][r] - mnew);
        ps += p;
        pv[f][r] = (bf16)p;
      }
    ps += __shfl_xor(ps, 16);
    ps += __shfl_xor(ps, 32);
    lsum = lsum * fsc + ps;
    mrow = mnew;

    #pragma unroll
    for (int f = 0; f < 4; ++f)
      *reinterpret_cast<bf16x4*>(&Ps[w][l15 * 72 + f * 16 + lg * 4]) = pv[f];

    #pragma unroll
    for (int r = 0; r < 4; ++r) {
      float fr = __shfl(fsc, lg * 4 + r);
      #pragma unroll
      for (int f = 0; f < 4; ++f) acc[f][r] *= fr;
    }

    #pragma unroll
    for (int kk = 0; kk < 2; ++kk) {
      bf16x8 pa = *reinterpret_cast<const bf16x8*>(&Ps[w][l15 * 72 + kk * 32 + lg * 8]);
      #pragma unroll
      for (int f = 0; f < 4; ++f) {
        bf16x8 vf = *reinterpret_cast<const bf16x8*>(
            &Vs[(f * 16 + l15) * 64 + (((kk * 4 + lg) ^ (l15 & 7)) << 3)]);
        acc[f] = __builtin_amdgcn_mfma_f32_16x16x32_bf16(pa, vf, acc[f], 0, 0, 0);
      }
    }
    __syncthreads();
  }

  float inv = 1.f / lsum;
  #pragma unroll
  for (int r = 0; r < 4; ++r) {
    float ir = __shfl(inv, lg * 4 + r);
    int srow = qt * 64 + w * 16 + lg * 4 + r;
    bf16* orow = outc + ((size_t)b * S + srow) * 3072 + col_off + h * 64 + l15;
    #pragma unroll
    for (int f = 0; f < 4; ++f) orow[f * 16] = (bf16)(acc[f][r] * ir);
  }
}

// ------------- RMSNorm in-place per (token, 1024-segment), bf16 ---------------
__global__ __launch_bounds__(256) void rmsnorm_kernel(
    bf16* data, const float* __restrict__ g0,
    const float* __restrict__ g1, const float* __restrict__ g2) {
  int token = blockIdx.x;
  int seg = blockIdx.y;
  const float* g = seg == 0 ? g0 : (seg == 1 ? g1 : g2);
  int tid = threadIdx.x;
  size_t base = (size_t)token * 3072 + seg * 1024;
  bf16x4 bv = reinterpret_cast<const bf16x4*>(data + base)[tid];
  f32x4 v;
  #pragma unroll
  for (int j = 0; j < 4; ++j) v[j] = (float)bv[j];
  float ss = v[0] * v[0] + v[1] * v[1] + v[2] * v[2] + v[3] * v[3];
  #pragma unroll
  for (int m = 1; m < 64; m <<= 1) ss += __shfl_xor(ss, m);
  __shared__ float red[4];
  if ((tid & 63) == 0) red[tid >> 6] = ss;
  __syncthreads();
  float tot = red[0] + red[1] + red[2] + red[3];
  float sc = rsqrtf(tot * (1.f / 1024.f) + 1.19209290e-07f);
  f32x4 gv = reinterpret_cast<const f32x4*>(g)[tid];
  bf16x4 o;
  #pragma unroll
  for (int j = 0; j < 4; ++j) o[j] = (bf16)(v[j] * sc * gv[j]);
  reinterpret_cast<bf16x4*>(data + base)[tid] = o;
}

// -------- silu(gate)*value : gv (8192x2048) bf16 -> (8192x1024) bf16 ----------
__global__ void silu_kernel(const bf16* __restrict__ gv, bf16* __restrict__ out) {
  int T = blockIdx.x * 256 + threadIdx.x;
  int row = T >> 8, c4 = (T & 255) * 4;
  bf16x4 g = *reinterpret_cast<const bf16x4*>(gv + (size_t)row * 2048 + c4);
  bf16x4 vv = *reinterpret_cast<const bf16x4*>(gv + (size_t)row * 2048 + 1024 + c4);
  bf16x4 o;
  #pragma unroll
  for (int j = 0; j < 4; ++j) {
    float x = (float)g[j];
    o[j] = (bf16)((x / (1.f + __expf(-x))) * (float)vv[j]);
  }
  *reinterpret_cast<bf16x4*>(out + (size_t)row * 1024 + c4) = o;
}

// =============================== launch ======================================
extern "C" void kernel_launch(void* const* d_in, const int* in_sizes, int n_in,
                              void* d_out, int out_size, void* d_ws, size_t ws_size,
                              hipStream_t stream) {
  (void)in_sizes; (void)n_in; (void)out_size; (void)ws_size;
  const float* x       = (const float*)d_in[0];
  const float* lm      = (const float*)d_in[1];
  const float* arch    = (const float*)d_in[2];
  const float* W_qkv   = (const float*)d_in[3];
  const float* W_lm    = (const float*)d_in[4];
  const float* W_arch  = (const float*)d_in[5];
  const float* W_o     = (const float*)d_in[6];
  const float* W_gate  = (const float*)d_in[7];
  const float* g_local = (const float*)d_in[8];
  const float* g_lm    = (const float*)d_in[9];
  const float* g_arch  = (const float*)d_in[10];
  float* out = (float*)d_out;

  char* ws = (char*)d_ws;
  size_t off = 0;
  auto alloc = [&](size_t bytes) -> void* {
    void* p = ws + off;
    off += (bytes + 255) & ~(size_t)255;
    return p;
  };
  // persistent
  bf16*  Wqkv_t   = (bf16*) alloc(3072ull * 1024 * 2);
  bf16*  Wlm_t    = (bf16*) alloc(2048ull * 1024 * 2);
  bf16*  Warch_t  = (bf16*) alloc(2048ull * 1024 * 2);
  bf16*  Wgate_t  = (bf16*) alloc(2048ull * 3072 * 2);
  bf16*  Wo_t     = (bf16*) alloc(1024ull * 1024 * 2);
  bf16*  lm_bf    = (bf16*) alloc(512ull * 1024 * 2);
  bf16*  arch_bf  = (bf16*) alloc(256ull * 1024 * 2);
  float* ropetab  = (float*)alloc(4096ull * 64 * 4);
  bf16*  Klm      = (bf16*) alloc(2ull * 16 * 256 * 64 * 2);
  bf16*  Vlm_t    = (bf16*) alloc(2ull * 16 * 64 * 256 * 2);
  bf16*  Ka       = (bf16*) alloc(2ull * 16 * 128 * 64 * 2);
  bf16*  Va_t     = (bf16*) alloc(2ull * 16 * 64 * 128 * 2);
  bf16*  lmkv_bf  = (bf16*) alloc(512ull * 2048 * 2);
  bf16*  akv_bf   = (bf16*) alloc(256ull * 2048 * 2);
  // region 1 (16 MB): x_bf, later gated
  char* R1 = (char*)alloc(8192ull * 1024 * 2);
  bf16* x_bf  = (bf16*)R1;
  bf16* gated = (bf16*)R1;
  // region 2 (48 MB): qkv_bf, later concat (bf16)
  char* R2 = (char*)alloc(8192ull * 3072 * 2);
  bf16* qkv_bf  = (bf16*)R2;
  bf16* concatb = (bf16*)R2;
  // region 3 (48 MB): Qb+Kb+Vt, later gate-GEMM output (32 MB)
  char* R3 = (char*)alloc(3ull * 16 * 1024 * 1024);
  bf16* Qb = (bf16*)R3;
  bf16* Kb = (bf16*)(R3 + 16ull * 1024 * 1024);
  bf16* Vt = (bf16*)(R3 + 32ull * 1024 * 1024);
  bf16* gv = (bf16*)R3;

  // 1. weight transposes + input casts + rope table
  transpose_cast<<<dim3(96, 32), dim3(32, 8), 0, stream>>>(W_qkv, Wqkv_t, 1024, 3072);
  transpose_cast<<<dim3(64, 32), dim3(32, 8), 0, stream>>>(W_lm, Wlm_t, 1024, 2048);
  transpose_cast<<<dim3(64, 32), dim3(32, 8), 0, stream>>>(W_arch, Warch_t, 1024, 2048);
  transpose_cast<<<dim3(64, 96), dim3(32, 8), 0, stream>>>(W_gate, Wgate_t, 3072, 2048);
  transpose_cast<<<dim3(32, 32), dim3(32, 8), 0, stream>>>(W_o, Wo_t, 1024, 1024);
  cast_f32_bf16<<<8192, 256, 0, stream>>>(x, x_bf, 8192 * 1024 / 4);
  cast_f32_bf16<<<512, 256, 0, stream>>>(lm, lm_bf, 512 * 1024 / 4);
  cast_f32_bf16<<<256, 256, 0, stream>>>(arch, arch_bf, 256 * 1024 / 4);
  rope_table<<<512, 256, 0, stream>>>(ropetab);

  // 2. projection GEMMs
  gemm256n128<bf16><<<32 * 24, 512, 0, stream>>>(x_bf, Wqkv_t, qkv_bf, 8192, 3072, 1024);
  gemm_bf16<bf16><<<dim3(16, 4), 256, 0, stream>>>(lm_bf, Wlm_t, lmkv_bf, 512, 2048, 1024);
  gemm_bf16<bf16><<<dim3(16, 2), 256, 0, stream>>>(arch_bf, Warch_t, akv_bf, 256, 2048, 1024);

  // 3. rope + head-split + V transposes
  rope_qk<<<16384, 256, 0, stream>>>(qkv_bf, ropetab, Qb, Kb);
  kv_post<<<dim3(64, 16, 2), 256, 0, stream>>>(qkv_bf, nullptr, Vt, 4096, 3072, 0, 2048);
  kv_post<<<dim3(4, 16, 2), 256, 0, stream>>>(lmkv_bf, Klm, Vlm_t, 256, 2048, 0, 1024);
  kv_post<<<dim3(2, 16, 2), 256, 0, stream>>>(akv_bf, Ka, Va_t, 128, 2048, 0, 1024);

  // 4. attentions -> concat
  attn_kernel<true><<<dim3(64, 16, 2), 256, 0, stream>>>(Qb, Kb, Vt, concatb, 4096, 4096, 0);
  attn_kernel<false><<<dim3(64, 16, 2), 256, 0, stream>>>(Qb, Klm, Vlm_t, concatb, 4096, 256, 1024);
  attn_kernel<false><<<dim3(64, 16, 2), 256, 0, stream>>>(Qb, Ka, Va_t, concatb, 4096, 128, 2048);

  // 5. per-branch RMSNorm in place
  rmsnorm_kernel<<<dim3(8192, 3), 256, 0, stream>>>(concatb, g_local, g_lm, g_arch);

  // 6. gate GEMM + silu + output GEMM
  gemm256<bf16><<<32 * 8, 512, 0, stream>>>(concatb, Wgate_t, gv, 8192, 2048, 3072);
  silu_kernel<<<8192, 256, 0, stream>>>(gv, gated);
  gemm256n128<float><<<32 * 8, 512, 0, stream>>>(gated, Wo_t, out, 8192, 1024, 1024);
}